// Round 1
// baseline (1122.095 us; speedup 1.0000x reference)
//
#include <hip/hip_runtime.h>

#define HH 1024
#define WW 1024
#define NB 16
#define NTH 3
#define NCOMBO (NB*NTH)
#define SHARP 10.0f
#define ACC_BYTES 4096
#define BAND 128

// Horizontal box sum of half-width p at (y,x) from a row-prefix-sum image P.
// Zero padding outside [0,W); rows outside [0,H) contribute 0.
__device__ __forceinline__ float hsum(const float* __restrict__ P, int y, int x, int p){
  if ((unsigned)y >= HH) return 0.f;
  const float* row = P + (size_t)y*WW;
  int hi = x + p; if (hi > WW-1) hi = WW-1;
  float s = row[hi];
  int lo = x - p - 1;
  if (lo >= 0) s -= row[lo];
  return s;
}

// Pass 1: per (row, combo) compute f=sigmoid(10(x-th)), o=(obs>th), and write
// inclusive row prefix sums Pf, Po to scratch.
__global__ __launch_bounds__(64) void fss_prefix(
    const float* __restrict__ fcst, const float* __restrict__ obs,
    float* __restrict__ scratch, int combo_base)
{
  const int row = blockIdx.x;
  const int lc  = blockIdx.y;
  const int combo = combo_base + lc;
  const int img = combo / NTH;
  const float th = 0.5f * (float)(combo % NTH);
  const int t = threadIdx.x;

  const float* fr  = fcst + ((size_t)img*HH + row)*WW;
  const float* orr = obs  + ((size_t)img*HH + row)*WW;
  float* Pf = scratch + (size_t)lc*2*HH*WW + (size_t)row*WW;
  float* Po = Pf + (size_t)HH*WW;

  float xf[16], xo[16];
  const float4* f4 = reinterpret_cast<const float4*>(fr)  + t*4;
  const float4* o4 = reinterpret_cast<const float4*>(orr) + t*4;
  #pragma unroll
  for (int q=0;q<4;q++){
    float4 a = f4[q]; xf[4*q]=a.x; xf[4*q+1]=a.y; xf[4*q+2]=a.z; xf[4*q+3]=a.w;
    float4 b = o4[q]; xo[4*q]=b.x; xo[4*q+1]=b.y; xo[4*q+2]=b.z; xo[4*q+3]=b.w;
  }
  float pf[16], po[16];
  float sf=0.f, so=0.f;
  #pragma unroll
  for (int j=0;j<16;j++){
    float fv = 1.0f/(1.0f + __expf(-SHARP*(xf[j]-th)));
    float ov = (xo[j] > th) ? 1.0f : 0.0f;
    sf += fv; pf[j]=sf;
    so += ov; po[j]=so;
  }
  // wave-wide inclusive scan of per-thread totals
  float csf=sf, cso=so;
  #pragma unroll
  for (int d=1; d<64; d<<=1){
    float nf = __shfl_up(csf, (unsigned)d, 64);
    float no = __shfl_up(cso, (unsigned)d, 64);
    if (t >= d){ csf += nf; cso += no; }
  }
  const float ef = csf - sf, eo = cso - so;  // exclusive carry
  float4* Pf4 = reinterpret_cast<float4*>(Pf) + t*4;
  float4* Po4 = reinterpret_cast<float4*>(Po) + t*4;
  #pragma unroll
  for (int q=0;q<4;q++){
    float4 a; a.x=pf[4*q]+ef; a.y=pf[4*q+1]+ef; a.z=pf[4*q+2]+ef; a.w=pf[4*q+3]+ef;
    float4 b; b.x=po[4*q]+eo; b.y=po[4*q+1]+eo; b.z=po[4*q+2]+eo; b.w=po[4*q+3]+eo;
    Pf4[q]=a; Po4[q]=b;
  }
}

// Pass 2: thread-per-column streaming down a row band; vertical sliding sums of
// horizontal box sums; accumulate the 6 statistics per combo.
__global__ __launch_bounds__(256) void fss_accum(
    const float* __restrict__ scratch, double* __restrict__ accum, int combo_base)
{
  const int x  = blockIdx.x*256 + threadIdx.x;
  const int y0 = blockIdx.y*BAND;
  const int lc = blockIdx.z;
  const int combo = combo_base + lc;
  const float* Pf = scratch + (size_t)lc*2*HH*WW;
  const float* Po = Pf + (size_t)HH*WW;

  float vs9f=0,vs9o=0,vs33f=0,vs33o=0;
  #pragma unroll 1
  for (int r=y0-4;  r<=y0+4;  ++r){ vs9f  += hsum(Pf,r,x,4);  vs9o  += hsum(Po,r,x,4); }
  #pragma unroll 1
  for (int r=y0-16; r<=y0+16; ++r){ vs33f += hsum(Pf,r,x,16); vs33o += hsum(Po,r,x,16); }

  float a1d=0,a1r=0,a9d=0,a9r=0,a33d=0,a33r=0;
  #pragma unroll 1
  for (int y=y0; y<y0+BAND; ++y){
    float f = hsum(Pf,y,x,0);   // P[y,x]-P[y,x-1] == f(y,x)
    float o = hsum(Po,y,x,0);
    float d1=f-o; a1d += d1*d1; a1r += f*f+o*o;
    float F9=vs9f*(1.f/81.f), O9=vs9o*(1.f/81.f);
    float d9=F9-O9; a9d += d9*d9; a9r += F9*F9+O9*O9;
    float F33=vs33f*(1.f/1089.f), O33=vs33o*(1.f/1089.f);
    float d33=F33-O33; a33d += d33*d33; a33r += F33*F33+O33*O33;
    vs9f  += hsum(Pf,y+5,x,4)   - hsum(Pf,y-4,x,4);
    vs9o  += hsum(Po,y+5,x,4)   - hsum(Po,y-4,x,4);
    vs33f += hsum(Pf,y+17,x,16) - hsum(Pf,y-16,x,16);
    vs33o += hsum(Po,y+17,x,16) - hsum(Po,y-16,x,16);
  }

  #pragma unroll
  for (int d=32; d; d>>=1){
    a1d += __shfl_down(a1d,(unsigned)d,64);  a1r += __shfl_down(a1r,(unsigned)d,64);
    a9d += __shfl_down(a9d,(unsigned)d,64);  a9r += __shfl_down(a9r,(unsigned)d,64);
    a33d+= __shfl_down(a33d,(unsigned)d,64); a33r+= __shfl_down(a33r,(unsigned)d,64);
  }
  __shared__ float red[4][6];
  const int wv = threadIdx.x>>6, ln = threadIdx.x&63;
  if (ln==0){ red[wv][0]=a1d; red[wv][1]=a1r; red[wv][2]=a9d;
              red[wv][3]=a9r; red[wv][4]=a33d; red[wv][5]=a33r; }
  __syncthreads();
  if (threadIdx.x < 6){
    double s = 0.0;
    #pragma unroll
    for (int w=0;w<4;w++) s += (double)red[w][threadIdx.x];
    atomicAdd(&accum[(size_t)combo*6 + threadIdx.x], s);
  }
}

__global__ void fss_final(const double* __restrict__ accum, float* __restrict__ out)
{
  if (threadIdx.x==0 && blockIdx.x==0){
    const double inv = 1.0/((double)HH*(double)WW);
    double total = 0.0;
    for (int th=0; th<NTH; ++th){
      for (int k=0; k<3; ++k){
        double s=0.0;
        for (int img=0; img<NB; ++img){
          const double* a = accum + ((size_t)(img*NTH+th))*6 + (size_t)k*2;
          double mse  = a[0]*inv;
          double mref = a[1]*inv;
          s += 1.0 - mse/(mref + 1e-8);
        }
        total += s/(double)NB;
      }
    }
    out[0] = (float)(1.0 - total/9.0);
  }
}

extern "C" void kernel_launch(void* const* d_in, const int* in_sizes, int n_in,
                              void* d_out, int out_size, void* d_ws, size_t ws_size,
                              hipStream_t stream)
{
  const float* fcst = (const float*)d_in[0];
  const float* obs  = (const float*)d_in[1];
  float* out = (float*)d_out;
  double* accum  = (double*)d_ws;
  float* scratch = (float*)((char*)d_ws + ACC_BYTES);
  const size_t combo_bytes = (size_t)2*HH*WW*sizeof(float);  // 8 MB per (img,th)
  size_t avail = ws_size > (size_t)ACC_BYTES ? ws_size - ACC_BYTES : 0;
  int per = (int)(avail / combo_bytes);
  if (per < 1) per = 1;
  if (per > NCOMBO) per = NCOMBO;

  hipMemsetAsync(d_ws, 0, ACC_BYTES, stream);
  for (int base = 0; base < NCOMBO; base += per){
    int n = NCOMBO - base; if (n > per) n = per;
    dim3 g1(HH, n);
    hipLaunchKernelGGL(fss_prefix, g1, dim3(64), 0, stream, fcst, obs, scratch, base);
    dim3 g2(WW/256, HH/BAND, n);
    hipLaunchKernelGGL(fss_accum, g2, dim3(256), 0, stream, scratch, accum, base);
  }
  hipLaunchKernelGGL(fss_final, dim3(1), dim3(64), 0, stream, accum, out);
}